// Round 2
// baseline (864.268 us; speedup 1.0000x reference)
//
#include <hip/hip_runtime.h>

#define BB 2
#define HH 16
#define SS 2048
#define DD 64
#define QT 64
#define KT 64

__device__ __forceinline__ unsigned rotl32(unsigned x, int r) {
  return (x << r) | (x >> (32 - r));
}

// JAX threefry2x32, key = jax.random.key(42) -> (k0=0, k1=42).
// Partitionable layout (default since jax 0.4.36): cipher input
// (x0 = hi32(i) = 0, x1 = lo32(i)); random bits for bit_width 32 are
// bits1 ^ bits2 (XOR-fold of both output words).
// keep = (bitcast((bits>>9)|0x3f800000) - 1.0f) < 0.9f.
__device__ __forceinline__ bool keep_mask(unsigned i) {
  const unsigned ks1 = 42u;
  const unsigned ks2 = 0x1BD11BDAu ^ 42u;  // C ^ k0 ^ k1, k0 = 0
  unsigned x0 = 0u;        // counts_hi(0) + ks0(0)
  unsigned x1 = i + ks1;   // counts_lo + ks1
  // group 0: rot 13,15,26,6
  x0 += x1; x1 = rotl32(x1, 13); x1 ^= x0;
  x0 += x1; x1 = rotl32(x1, 15); x1 ^= x0;
  x0 += x1; x1 = rotl32(x1, 26); x1 ^= x0;
  x0 += x1; x1 = rotl32(x1,  6); x1 ^= x0;
  x0 += ks1; x1 += ks2 + 1u;
  // group 1: rot 17,29,16,24
  x0 += x1; x1 = rotl32(x1, 17); x1 ^= x0;
  x0 += x1; x1 = rotl32(x1, 29); x1 ^= x0;
  x0 += x1; x1 = rotl32(x1, 16); x1 ^= x0;
  x0 += x1; x1 = rotl32(x1, 24); x1 ^= x0;
  x0 += ks2; x1 += 2u;           // ks0 + 2
  // group 2: rot 13,15,26,6
  x0 += x1; x1 = rotl32(x1, 13); x1 ^= x0;
  x0 += x1; x1 = rotl32(x1, 15); x1 ^= x0;
  x0 += x1; x1 = rotl32(x1, 26); x1 ^= x0;
  x0 += x1; x1 = rotl32(x1,  6); x1 ^= x0;
  /* x0 += ks0 (=0) */ x1 += ks1 + 3u;
  // group 3: rot 17,29,16,24
  x0 += x1; x1 = rotl32(x1, 17); x1 ^= x0;
  x0 += x1; x1 = rotl32(x1, 29); x1 ^= x0;
  x0 += x1; x1 = rotl32(x1, 16); x1 ^= x0;
  x0 += x1; x1 = rotl32(x1, 24); x1 ^= x0;
  x0 += ks1; x1 += ks2 + 4u;
  // group 4: rot 13,15,26,6
  x0 += x1; x1 = rotl32(x1, 13); x1 ^= x0;
  x0 += x1; x1 = rotl32(x1, 15); x1 ^= x0;
  x0 += x1; x1 = rotl32(x1, 26); x1 ^= x0;
  x0 += x1; x1 = rotl32(x1,  6); x1 ^= x0;
  x0 += ks2; x1 += 5u;           // final key injection (ks2, ks0+5)
  unsigned bits = x0 ^ x1;       // bits1 ^ bits2 (partitionable 32-bit fold)
  float u = __uint_as_float((bits >> 9) | 0x3f800000u) - 1.0f;
  return u < 0.9f;
}

// One workgroup per (b*H+h, 64-query tile). 256 threads = 4 waves.
// Thread t -> (qb = t>>4, cb = t&15): owns q rows qb*4..+3 and a 4-wide
// column block (k cols in score phase, d cols in PV phase).
__global__ __launch_bounds__(256, 2)
void fused_attn_dropout(const float* __restrict__ Qg, const float* __restrict__ Kg,
                        const float* __restrict__ Vg, float* __restrict__ Og) {
  __shared__ float Qs[QT][DD];   // [q][d]
  __shared__ float Ktr[DD][KT];  // [d][k]  (transposed for conflict-free float4 reads)
  __shared__ float Vs[KT][DD];   // [k][d]
  __shared__ float Ps[QT][KT];   // [q][k]  dropped, unnormalized p

  const int t   = threadIdx.x;
  const int qt0 = blockIdx.x * QT;
  const int bh  = blockIdx.y;          // b*H + h
  const int b   = bh >> 4, h = bh & 15;

  const int qb = t >> 4;   // 0..15
  const int cb = t & 15;   // 0..15

  // input row base for sequence position s: [B,S,H,D]
  auto gidx = [&](int s) { return (((size_t)b * SS + s) * HH + h) * DD; };

  // ---- stage Q tile ----
  {
    const int r  = t >> 2;           // 0..63
    const int c0 = (t & 3) << 4;     // 0,16,32,48
    const float* src = Qg + gidx(qt0 + r) + c0;
    #pragma unroll
    for (int u4 = 0; u4 < 4; ++u4) {
      float4 qv = ((const float4*)src)[u4];
      *(float4*)&Qs[r][c0 + u4 * 4] = qv;
    }
  }

  float mrow[4], lrow[4], acc[4][4];
  #pragma unroll
  for (int j = 0; j < 4; ++j) {
    mrow[j] = -1e30f; lrow[j] = 0.f;
    #pragma unroll
    for (int c = 0; c < 4; ++c) acc[j][c] = 0.f;
  }

  for (int kt = 0; kt < SS / KT; ++kt) {
    __syncthreads();  // previous PV done reading Ktr/Vs/Ps
    // ---- stage K (transposed) and V ----
    {
      const int r  = t >> 2;
      const int c0 = (t & 3) << 4;
      const float* ksrc = Kg + gidx(kt * KT + r) + c0;
      const float* vsrc = Vg + gidx(kt * KT + r) + c0;
      float ka[16];
      #pragma unroll
      for (int u4 = 0; u4 < 4; ++u4) {
        float4 kv = ((const float4*)ksrc)[u4];
        ka[u4 * 4 + 0] = kv.x; ka[u4 * 4 + 1] = kv.y;
        ka[u4 * 4 + 2] = kv.z; ka[u4 * 4 + 3] = kv.w;
        float4 vv = ((const float4*)vsrc)[u4];
        *(float4*)&Vs[r][c0 + u4 * 4] = vv;
      }
      #pragma unroll
      for (int u1 = 0; u1 < 16; ++u1) Ktr[c0 + u1][r] = ka[u1];
    }
    __syncthreads();

    // ---- QK^T: 4x4 scores per thread ----
    float s[4][4];
    #pragma unroll
    for (int j = 0; j < 4; ++j)
      #pragma unroll
      for (int c = 0; c < 4; ++c) s[j][c] = 0.f;

    #pragma unroll
    for (int d0 = 0; d0 < DD; d0 += 4) {
      float qa[4][4], kc[4][4];
      #pragma unroll
      for (int j = 0; j < 4; ++j) {
        float4 qv = *(const float4*)&Qs[qb * 4 + j][d0];
        qa[j][0] = qv.x; qa[j][1] = qv.y; qa[j][2] = qv.z; qa[j][3] = qv.w;
      }
      #pragma unroll
      for (int dd = 0; dd < 4; ++dd) {
        float4 kv = *(const float4*)&Ktr[d0 + dd][cb * 4];
        kc[dd][0] = kv.x; kc[dd][1] = kv.y; kc[dd][2] = kv.z; kc[dd][3] = kv.w;
      }
      #pragma unroll
      for (int j = 0; j < 4; ++j)
        #pragma unroll
        for (int c = 0; c < 4; ++c)
          s[j][c] += qa[j][0] * kc[0][c] + qa[j][1] * kc[1][c]
                   + qa[j][2] * kc[2][c] + qa[j][3] * kc[3][c];
    }

    // ---- online softmax + dropout, write P to LDS ----
    float rfac[4];
    const unsigned rowbase0 =
        ((unsigned)bh * SS + (unsigned)(qt0 + qb * 4)) * SS +
        (unsigned)(kt * KT + cb * 4);
    #pragma unroll
    for (int j = 0; j < 4; ++j) {
      float p[4];
      #pragma unroll
      for (int c = 0; c < 4; ++c) p[c] = s[j][c] * 0.125f;  // scale = 1/sqrt(64)
      float tm = fmaxf(fmaxf(p[0], p[1]), fmaxf(p[2], p[3]));
      for (int off = 1; off < 16; off <<= 1)
        tm = fmaxf(tm, __shfl_xor(tm, off, 64));
      const float mn = fmaxf(mrow[j], tm);
      const float rr = __expf(mrow[j] - mn);
      float ps = 0.f;
      #pragma unroll
      for (int c = 0; c < 4; ++c) { p[c] = __expf(p[c] - mn); ps += p[c]; }
      for (int off = 1; off < 16; off <<= 1)
        ps += __shfl_xor(ps, off, 64);
      lrow[j] = lrow[j] * rr + ps;   // denominator: un-dropped sum
      mrow[j] = mn;
      rfac[j] = rr;
      const unsigned ib = rowbase0 + (unsigned)j * SS;
      #pragma unroll
      for (int c = 0; c < 4; ++c)
        if (!keep_mask(ib + c)) p[c] = 0.f;
      float4 pw; pw.x = p[0]; pw.y = p[1]; pw.z = p[2]; pw.w = p[3];
      *(float4*)&Ps[qb * 4 + j][cb * 4] = pw;
    }
    __syncthreads();

    // ---- PV: rescale acc, accumulate P @ V ----
    #pragma unroll
    for (int j = 0; j < 4; ++j)
      #pragma unroll
      for (int c = 0; c < 4; ++c) acc[j][c] *= rfac[j];

    #pragma unroll 4
    for (int k0 = 0; k0 < KT; k0 += 4) {
      float va[4][4];
      #pragma unroll
      for (int kk = 0; kk < 4; ++kk) {
        float4 vv = *(const float4*)&Vs[k0 + kk][cb * 4];
        va[kk][0] = vv.x; va[kk][1] = vv.y; va[kk][2] = vv.z; va[kk][3] = vv.w;
      }
      #pragma unroll
      for (int j = 0; j < 4; ++j) {
        float4 pv4 = *(const float4*)&Ps[qb * 4 + j][k0];
        float pa[4]; pa[0] = pv4.x; pa[1] = pv4.y; pa[2] = pv4.z; pa[3] = pv4.w;
        #pragma unroll
        for (int kk = 0; kk < 4; ++kk)
          #pragma unroll
          for (int c = 0; c < 4; ++c)
            acc[j][c] += pa[kk] * va[kk][c];
      }
    }
  }

  // ---- epilogue: normalize (1/l) and inverse-keep-prob (1/0.9), write out ----
  #pragma unroll
  for (int j = 0; j < 4; ++j) {
    const float inv = 1.0f / (lrow[j] * 0.9f);
    float4 o;
    o.x = acc[j][0] * inv; o.y = acc[j][1] * inv;
    o.z = acc[j][2] * inv; o.w = acc[j][3] * inv;
    *(float4*)&Og[((size_t)bh * SS + (qt0 + qb * 4 + j)) * DD + cb * 4] = o;
  }
}

extern "C" void kernel_launch(void* const* d_in, const int* in_sizes, int n_in,
                              void* d_out, int out_size, void* d_ws, size_t ws_size,
                              hipStream_t stream) {
  const float* Q = (const float*)d_in[0];
  const float* K = (const float*)d_in[1];
  const float* V = (const float*)d_in[2];
  float* O = (float*)d_out;
  dim3 grid(SS / QT, BB * HH);
  fused_attn_dropout<<<grid, dim3(256), 0, stream>>>(Q, K, V, O);
}

// Round 3
// 373.508 us; speedup vs baseline: 2.3139x; 2.3139x over previous
//
#include <hip/hip_runtime.h>

#define BB 2
#define HH 16
#define SS 2048
#define DD 64
#define QT 64
#define KT 64
#define LP 72   // padded LDS row stride in halfs (144 B -> 2-way conflicts only)

using bf16x8 = __attribute__((ext_vector_type(8))) short;
using half8  = __attribute__((ext_vector_type(8))) _Float16;
using f32x4  = __attribute__((ext_vector_type(4))) float;

__device__ __forceinline__ unsigned rotl32(unsigned x, int r) {
  return (x << r) | (x >> (32 - r));
}

// JAX threefry2x32, key (0,42), partitionable: input (0, i), bits = out0^out1.
// keep ⟺ (bitcast((bits>>9)|0x3f800000)-1.0f) < 0.9f ⟺ bits < 0xE6666600
// (exact: f-1 is Sterbenz-exact; threshold = 0x733333<<9).
__device__ __forceinline__ bool keep_mask(unsigned i) {
  const unsigned ks1 = 42u;
  const unsigned ks2 = 0x1BD11BDAu ^ 42u;
  unsigned x0 = 0u;
  unsigned x1 = i + ks1;
  x0 += x1; x1 = rotl32(x1, 13); x1 ^= x0;
  x0 += x1; x1 = rotl32(x1, 15); x1 ^= x0;
  x0 += x1; x1 = rotl32(x1, 26); x1 ^= x0;
  x0 += x1; x1 = rotl32(x1,  6); x1 ^= x0;
  x0 += ks1; x1 += ks2 + 1u;
  x0 += x1; x1 = rotl32(x1, 17); x1 ^= x0;
  x0 += x1; x1 = rotl32(x1, 29); x1 ^= x0;
  x0 += x1; x1 = rotl32(x1, 16); x1 ^= x0;
  x0 += x1; x1 = rotl32(x1, 24); x1 ^= x0;
  x0 += ks2; x1 += 2u;
  x0 += x1; x1 = rotl32(x1, 13); x1 ^= x0;
  x0 += x1; x1 = rotl32(x1, 15); x1 ^= x0;
  x0 += x1; x1 = rotl32(x1, 26); x1 ^= x0;
  x0 += x1; x1 = rotl32(x1,  6); x1 ^= x0;
  x1 += ks1 + 3u;
  x0 += x1; x1 = rotl32(x1, 17); x1 ^= x0;
  x0 += x1; x1 = rotl32(x1, 29); x1 ^= x0;
  x0 += x1; x1 = rotl32(x1, 16); x1 ^= x0;
  x0 += x1; x1 = rotl32(x1, 24); x1 ^= x0;
  x0 += ks1; x1 += ks2 + 4u;
  x0 += x1; x1 = rotl32(x1, 13); x1 ^= x0;
  x0 += x1; x1 = rotl32(x1, 15); x1 ^= x0;
  x0 += x1; x1 = rotl32(x1, 26); x1 ^= x0;
  x0 += x1; x1 = rotl32(x1,  6); x1 ^= x0;
  x0 += ks2; x1 += 5u;
  return (x0 ^ x1) < 0xE6666600u;
}

// grid (32, 32): one block per (64-q tile, b*H+h). 4 waves; wave w owns
// q-rows [16w,16w+16). Lane: l15 = l&15, hi4 = l>>4.
// MFMA 16x16x32 frags: A row=l15,k=hi4*8+j; B col=l15,k=hi4*8+j;
// D col=l15, row=hi4*4+reg (m89-verified).
__global__ __launch_bounds__(256, 2)
void fused_attn_mfma(const float* __restrict__ Qg, const float* __restrict__ Kg,
                     const float* __restrict__ Vg, float* __restrict__ Og) {
  __shared__ __attribute__((aligned(16))) unsigned short Ks_hi[KT][LP];
  __shared__ __attribute__((aligned(16))) unsigned short Ks_lo[KT][LP];
  __shared__ __attribute__((aligned(16))) _Float16 Vt_hi[DD][LP];  // [d][k]
  __shared__ __attribute__((aligned(16))) _Float16 Vt_lo[DD][LP];
  __shared__ __attribute__((aligned(16))) _Float16 Ps[QT][LP];

  const int t   = threadIdx.x;
  const int w   = t >> 6;
  const int l   = t & 63;
  const int l15 = l & 15;
  const int hi4 = l >> 4;

  const int qt0 = blockIdx.x * QT;
  const int bh  = blockIdx.y;
  const int b   = bh >> 4, h = bh & 15;

  auto gidx = [&](int s) { return (((size_t)b * SS + s) * HH + h) * DD; };

  // ---- Q A-fragments in registers (bf16 hi/lo), rows = qt0+16w+l15 ----
  bf16x8 qh[2], ql[2];
  {
    const float* qp = Qg + gidx(qt0 + 16 * w + l15) + hi4 * 8;
    #pragma unroll
    for (int c = 0; c < 2; ++c) {
      float f[8];
      *(float4*)&f[0] = *(const float4*)(qp + c * 32);
      *(float4*)&f[4] = *(const float4*)(qp + c * 32 + 4);
      #pragma unroll
      for (int j = 0; j < 8; ++j) {
        unsigned u = __float_as_uint(f[j]);
        qh[c][j] = (short)(u >> 16);
        float lo = f[j] - __uint_as_float(u & 0xFFFF0000u);
        ql[c][j] = (short)(__float_as_uint(lo) >> 16);
      }
    }
  }

  f32x4 o[4];
  float mrow[4], lrow[4];
  #pragma unroll
  for (int i = 0; i < 4; ++i) { o[i] = (f32x4){0.f,0.f,0.f,0.f}; mrow[i] = -1e30f; lrow[i] = 0.f; }

  // dropout flat-index base for this lane's D-layout rows
  const unsigned fb = ((unsigned)bh * SS + (unsigned)(qt0 + 16 * w + hi4 * 4)) * SS + (unsigned)l15;

  for (int kt = 0; kt < SS / KT; ++kt) {
    __syncthreads();  // prev iter done reading Ks/Vt/Ps

    // ---- stage K tile as bf16 hi/lo [k][d] ----
    {
      const int r = t >> 2, c0 = (t & 3) * 16;
      const float* kp = Kg + gidx(kt * KT + r) + c0;
      unsigned short khs[16], kls[16];
      #pragma unroll
      for (int u4 = 0; u4 < 4; ++u4) {
        float4 kv = *(const float4*)(kp + u4 * 4);
        float ff[4] = {kv.x, kv.y, kv.z, kv.w};
        #pragma unroll
        for (int j = 0; j < 4; ++j) {
          unsigned u = __float_as_uint(ff[j]);
          khs[u4 * 4 + j] = (unsigned short)(u >> 16);
          float lo = ff[j] - __uint_as_float(u & 0xFFFF0000u);
          kls[u4 * 4 + j] = (unsigned short)(__float_as_uint(lo) >> 16);
        }
      }
      *(bf16x8*)&Ks_hi[r][c0]     = *(bf16x8*)&khs[0];
      *(bf16x8*)&Ks_hi[r][c0 + 8] = *(bf16x8*)&khs[8];
      *(bf16x8*)&Ks_lo[r][c0]     = *(bf16x8*)&kls[0];
      *(bf16x8*)&Ks_lo[r][c0 + 8] = *(bf16x8*)&kls[8];
    }
    // ---- stage V transposed as fp16 hi/lo [d][k] (wave-conflict-free u16) ----
    {
      const int rV = t & 63, c0V = (t >> 6) * 16;
      const float* vp = Vg + gidx(kt * KT + rV) + c0V;
      #pragma unroll
      for (int u4 = 0; u4 < 4; ++u4) {
        float4 vv = *(const float4*)(vp + u4 * 4);
        float ff[4] = {vv.x, vv.y, vv.z, vv.w};
        #pragma unroll
        for (int j = 0; j < 4; ++j) {
          _Float16 hh = (_Float16)ff[j];
          _Float16 ll = (_Float16)(ff[j] - (float)hh);
          Vt_hi[c0V + u4 * 4 + j][rV] = hh;
          Vt_lo[c0V + u4 * 4 + j][rV] = ll;
        }
      }
    }
    __syncthreads();

    // ---- QK^T via MFMA, 3-term bf16 split ----
    f32x4 s4[4];
    #pragma unroll
    for (int k4 = 0; k4 < 4; ++k4) {
      f32x4 a = (f32x4){0.f,0.f,0.f,0.f};
      #pragma unroll
      for (int c = 0; c < 2; ++c) {
        bf16x8 kh = *(const bf16x8*)&Ks_hi[k4 * 16 + l15][c * 32 + hi4 * 8];
        bf16x8 kl = *(const bf16x8*)&Ks_lo[k4 * 16 + l15][c * 32 + hi4 * 8];
        a = __builtin_amdgcn_mfma_f32_16x16x32_bf16(qh[c], kh, a, 0, 0, 0);
        a = __builtin_amdgcn_mfma_f32_16x16x32_bf16(qh[c], kl, a, 0, 0, 0);
        a = __builtin_amdgcn_mfma_f32_16x16x32_bf16(ql[c], kh, a, 0, 0, 0);
      }
      s4[k4] = a;
    }

    // ---- threefry keep bits first (VALU hides shuffle latency below) ----
    unsigned kmask = 0;
    {
      const unsigned ib = fb + (unsigned)(kt * KT);
      #pragma unroll
      for (int r4 = 0; r4 < 4; ++r4)
        #pragma unroll
        for (int k4 = 0; k4 < 4; ++k4)
          kmask |= (keep_mask(ib + (unsigned)(r4 * SS + k4 * 16)) ? 1u : 0u) << (r4 * 4 + k4);
    }

    // ---- online softmax per owned q-row; dropped fp16 P to LDS ----
    float rfac[4];
    #pragma unroll
    for (int r4 = 0; r4 < 4; ++r4) {
      float tm = fmaxf(fmaxf(s4[0][r4], s4[1][r4]), fmaxf(s4[2][r4], s4[3][r4]));
      #pragma unroll
      for (int off = 1; off < 16; off <<= 1)
        tm = fmaxf(tm, __shfl_xor(tm, off, 64));
      tm *= 0.125f;
      const float mn = fmaxf(mrow[r4], tm);
      const float rr = __expf(mrow[r4] - mn);
      float p[4], ps = 0.f;
      #pragma unroll
      for (int k4 = 0; k4 < 4; ++k4) {
        p[k4] = __expf(fmaf(s4[k4][r4], 0.125f, -mn));
        ps += p[k4];
      }
      #pragma unroll
      for (int off = 1; off < 16; off <<= 1)
        ps += __shfl_xor(ps, off, 64);
      lrow[r4] = lrow[r4] * rr + ps;   // denominator: un-dropped sum
      mrow[r4] = mn;
      rfac[r4] = rr;
      #pragma unroll
      for (int k4 = 0; k4 < 4; ++k4) {
        _Float16 ph = ((kmask >> (r4 * 4 + k4)) & 1u) ? (_Float16)p[k4] : (_Float16)0.f;
        Ps[16 * w + hi4 * 4 + r4][k4 * 16 + l15] = ph;
      }
    }
    __syncthreads();  // P visible for A-frag reads

    // ---- PV via MFMA: P(fp16) x (V_hi + V_lo) ----
    half8 pa[2];
    #pragma unroll
    for (int c = 0; c < 2; ++c)
      pa[c] = *(const half8*)&Ps[16 * w + l15][c * 32 + hi4 * 8];
    #pragma unroll
    for (int dt = 0; dt < 4; ++dt) {
      f32x4 a = o[dt];
      #pragma unroll
      for (int i = 0; i < 4; ++i) a[i] *= rfac[i];
      #pragma unroll
      for (int c = 0; c < 2; ++c) {
        half8 vh = *(const half8*)&Vt_hi[dt * 16 + l15][c * 32 + hi4 * 8];
        half8 vl = *(const half8*)&Vt_lo[dt * 16 + l15][c * 32 + hi4 * 8];
        a = __builtin_amdgcn_mfma_f32_16x16x32_f16(pa[c], vh, a, 0, 0, 0);
        a = __builtin_amdgcn_mfma_f32_16x16x32_f16(pa[c], vl, a, 0, 0, 0);
      }
      o[dt] = a;
    }
  }

  // ---- epilogue: /(l * 0.9), write [B,H,S,D] ----
  #pragma unroll
  for (int r4 = 0; r4 < 4; ++r4) {
    const float inv = 1.0f / (lrow[r4] * 0.9f);
    const size_t ob = ((size_t)bh * SS + (qt0 + 16 * w + hi4 * 4 + r4)) * DD + l15;
    #pragma unroll
    for (int dt = 0; dt < 4; ++dt)
      Og[ob + dt * 16] = o[dt][r4] * inv;
  }
}

extern "C" void kernel_launch(void* const* d_in, const int* in_sizes, int n_in,
                              void* d_out, int out_size, void* d_ws, size_t ws_size,
                              hipStream_t stream) {
  const float* Q = (const float*)d_in[0];
  const float* K = (const float*)d_in[1];
  const float* V = (const float*)d_in[2];
  float* O = (float*)d_out;
  dim3 grid(SS / QT, BB * HH);
  fused_attn_mfma<<<grid, dim3(256), 0, stream>>>(Q, K, V, O);
}